// Round 1
// baseline (121.968 us; speedup 1.0000x reference)
//
#include <hip/hip_runtime.h>

// YOLOv1 loss: N=8192, S=7, C=30 -> 401408 cells, 96.4 MB read, scalar out.
// Pure streaming reduction, zero reuse -> NO LDS staging. One thread per
// cell; each thread loads its 120-B p-record and 120-B t-record as
// 15+15 float2 (8-B aligned for every cell since stride 120 % 8 == 0).
// A wave's loads cover a contiguous 7.68 KB window -> every cache line
// fully consumed, traffic = exactly 2x48.2 MB. Latency hidden by TLP:
// __launch_bounds__(256,4) -> >=16 waves/CU (2x the old LDS-pipelined
// kernel's 8/CU), 30 independent loads in flight per thread.
// Reduction: wave shuffle -> 4 floats in LDS -> 1 atomicAdd per block
// (1568 atomics total, partials pre-scaled by 1/N).

#define NCH 30
#define CELLS_PER_SAMPLE 49

__device__ __forceinline__ float iou_f(float a0, float a1, float a2, float a3,
                                       float b0, float b1, float b2, float b3) {
    float xl = fmaxf(a0, b0);
    float yt = fmaxf(a1, b1);
    float xr = fminf(a2, b2);
    float yb = fminf(a3, b3);
    float ix = fmaxf(xr - xl, 0.0f);
    float iy = fmaxf(yb - yt, 0.0f);
    float inter = ix * iy;
    float aa = fabsf((a2 - a0) * (a3 - a1));
    float ba = fabsf((b2 - b0) * (b3 - b1));
    return inter / (aa + ba - inter + 1e-7f);
}

__device__ __forceinline__ float cell_loss_f(const float* __restrict__ pv,
                                             const float* __restrict__ tv,
                                             int cell) {
    int rem = cell % CELLS_PER_SAMPLE;
    int ci = rem / 7;   // row
    int cj = rem % 7;   // col

    float ltx = (float)cj / 7.0f;
    float lty = (float)ci / 7.0f;

    float coord = (tv[4] > 0.0f) ? 1.0f : 0.0f;
    float noobj = (tv[4] == 0.0f) ? 1.0f : 0.0f;

    // predicted box 1
    float b1x1 = ltx + pv[0] / 7.0f - pv[2] * 0.5f;
    float b1y1 = lty + pv[1] / 7.0f - pv[3] * 0.5f;
    float b1x2 = pv[2] + b1x1;
    float b1y2 = pv[3] + b1y1;

    // predicted box 2 (faithful: p[5:7]*(1/S - 0.5))
    const float C2 = (float)(1.0 / 7.0 - 0.5);
    float b2x1 = ltx + pv[5] * C2;
    float b2y1 = lty + pv[6] * C2;
    float b2x2 = pv[7] + b2x1;
    float b2y2 = pv[8] + b2y1;

    // target box
    float tbx1 = ltx + tv[0] / 7.0f - tv[2] * 0.5f;
    float tby1 = lty + tv[1] / 7.0f - tv[3] * 0.5f;
    float tbx2 = tv[2] + tbx1;
    float tby2 = tv[3] + tby1;

    float iou1 = iou_f(b1x1, b1y1, b1x2, b1y2, tbx1, tby1, tbx2, tby2);
    float iou2 = iou_f(b2x1, b2y1, b2x2, b2y2, tbx1, tby1, tbx2, tby2);

    bool sel = (iou1 >= iou2);
    float bx = sel ? pv[0] : pv[5];
    float by = sel ? pv[1] : pv[6];
    float bw = sel ? pv[2] : pv[7];
    float bh = sel ? pv[3] : pv[8];
    float bc = sel ? pv[4] : pv[9];

    float dx = bx - tv[0];
    float dy = by - tv[1];
    float xy_se = dx * dx + dy * dy;

    float sw = (bw > 0.0f) ? 1.0f : ((bw < 0.0f) ? -1.0f : 0.0f);
    float sh = (bh > 0.0f) ? 1.0f : ((bh < 0.0f) ? -1.0f : 0.0f);
    float dw = sw * sqrtf(fabsf(bw)) - sqrtf(tv[2]);
    float dh = sh * sqrtf(fabsf(bh)) - sqrtf(tv[3]);
    float wh_se = dw * dw + dh * dh;

    float mio = fmaxf(iou1, iou2);
    float dob = mio - bc;
    float obj_se = dob * dob;

    float d4 = pv[4] - tv[4];
    float d9 = pv[9] - tv[9];
    float noobj_se = d4 * d4 + d9 * d9;

    float lab = 0.0f;
    #pragma unroll
    for (int k = 10; k < NCH; ++k) {
        float d = pv[k] - tv[k];
        lab += d * d;
    }

    return coord * (5.0f * (xy_se + wh_se) + obj_se + lab)
         + 0.5f * noobj * noobj_se;
}

__global__ __launch_bounds__(256, 4) void yolo_loss_kernel(
    const float* __restrict__ p, const float* __restrict__ t,
    float* __restrict__ out, int ncells, float inv_n)
{
    const int tid  = threadIdx.x;
    const int cell = blockIdx.x * 256 + tid;

    float acc = 0.0f;
    if (cell < ncells) {
        const float2* __restrict__ pp =
            (const float2*)(p + (size_t)cell * NCH);
        const float2* __restrict__ tp =
            (const float2*)(t + (size_t)cell * NCH);

        float pv[NCH], tv[NCH];
        #pragma unroll
        for (int k = 0; k < NCH / 2; ++k) {
            float2 a = pp[k];
            float2 b = tp[k];
            pv[2 * k] = a.x; pv[2 * k + 1] = a.y;
            tv[2 * k] = b.x; tv[2 * k + 1] = b.y;
        }

        acc = cell_loss_f(pv, tv, cell) * inv_n;
    }

    // wave-64 shuffle reduction
    #pragma unroll
    for (int off = 32; off > 0; off >>= 1)
        acc += __shfl_down(acc, off, 64);

    __shared__ float wave_sums[4];
    const int lane = tid & 63;
    const int wid  = tid >> 6;
    if (lane == 0) wave_sums[wid] = acc;
    __syncthreads();
    if (tid == 0) {
        atomicAdd(out, wave_sums[0] + wave_sums[1] + wave_sums[2] + wave_sums[3]);
    }
}

extern "C" void kernel_launch(void* const* d_in, const int* in_sizes, int n_in,
                              void* d_out, int out_size, void* d_ws, size_t ws_size,
                              hipStream_t stream) {
    const float* p = (const float*)d_in[0];   // modely [N,7,7,30] f32
    const float* t = (const float*)d_in[1];   // targety [N,7,7,30] f32
    float* out = (float*)d_out;

    int ncells = in_sizes[0] / NCH;                  // 401408
    int nsamples = ncells / CELLS_PER_SAMPLE;        // 8192
    int nblocks = (ncells + 255) / 256;              // 1568

    // d_out is poisoned before every timed launch — zero it first.
    hipMemsetAsync(out, 0, sizeof(float) * (size_t)out_size, stream);

    yolo_loss_kernel<<<nblocks, 256, 0, stream>>>(
        p, t, out, ncells, 1.0f / (float)nsamples);
}

// Round 2
// 113.308 us; speedup vs baseline: 1.0764x; 1.0764x over previous
//
#include <hip/hip_runtime.h>

// YOLOv1 loss: N=8192, S=7, C=30 -> 401408 cells, 96.4 MB read, scalar out.
// Streaming reduction at HBM roofline requires COALESCED loads; the 120-B
// AoS record forces a transpose -> stage via global_load_lds (16-B width
// only, HW-verified) into LDS, then each thread reads its cell's 30 floats
// from LDS (stride 120 B = 4-way bank alias on ds_read_b64, 1.58x, and LDS
// has ~11x headroom over HBM here -> irrelevant).
//
// Structure: 512 blocks x 256 threads (2 blocks/CU, LDS 61456 B/block).
//   Tile = 128 cells = 30720 B (p 15360 + t 15360) = 30 x 1024-B full-wave
//   global_load_lds_dwordx4 transfers, round-robined over 4 waves
//   (compute waves 0,1 take 7; idle waves 2,3 take 8).
//   Double buffer; ONE __syncthreads per tile (its vmcnt(0) drain is the
//   buffer-ready gate); next-tile stage issues right after the barrier so
//   HBM latency hides under compute + the co-resident block.
//   In-flight/CU at steady state ~61 KB >> ~9 KB Little's-law need.

#define NCH 30
#define CELLS_PER_SAMPLE 49
#define TILE_CELLS 128
#define ARR_TILE_BYTES (TILE_CELLS * NCH * 4)   // 15360
#define TILE_BYTES (2 * ARR_TILE_BYTES)         // 30720
#define NXFER 30                                // 1024-B wave transfers per tile
#define NBLOCKS 512

__device__ __forceinline__ void gl_lds16(const char* g, char* l) {
    __builtin_amdgcn_global_load_lds(
        (const __attribute__((address_space(1))) unsigned int*)g,
        (__attribute__((address_space(3))) unsigned int*)l, 16, 0, 0);
}

// Stage one 30720-B tile (p half then t half, LDS-linear) with this wave's
// share of the 30 wave-wide 1024-B transfers. LDS dest is wave-uniform
// base + lane*16 (hardware adds the lane offset).
__device__ __forceinline__ void stage_tile(const char* __restrict__ p,
                                           const char* __restrict__ t,
                                           int g, char* ldst, int xr, int lane) {
    size_t base = (size_t)g * ARR_TILE_BYTES;
    #pragma unroll
    for (int j0 = 0; j0 < 8; ++j0) {
        int j = xr + j0 * 4;
        if (j < NXFER) {
            const char* src = (j < 15)
                ? p + base + (size_t)j * 1024 + (size_t)lane * 16
                : t + base + (size_t)(j - 15) * 1024 + (size_t)lane * 16;
            gl_lds16(src, ldst + j * 1024);
        }
    }
}

__device__ __forceinline__ float iou_f(float a0, float a1, float a2, float a3,
                                       float b0, float b1, float b2, float b3) {
    float xl = fmaxf(a0, b0);
    float yt = fmaxf(a1, b1);
    float xr = fminf(a2, b2);
    float yb = fminf(a3, b3);
    float ix = fmaxf(xr - xl, 0.0f);
    float iy = fmaxf(yb - yt, 0.0f);
    float inter = ix * iy;
    float aa = fabsf((a2 - a0) * (a3 - a1));
    float ba = fabsf((b2 - b0) * (b3 - b1));
    return inter / (aa + ba - inter + 1e-7f);
}

__device__ __forceinline__ float cell_loss_f(const float* __restrict__ pv,
                                             const float* __restrict__ tv,
                                             int cell) {
    int rem = cell % CELLS_PER_SAMPLE;
    int ci = rem / 7;   // row
    int cj = rem % 7;   // col

    float ltx = (float)cj / 7.0f;
    float lty = (float)ci / 7.0f;

    float coord = (tv[4] > 0.0f) ? 1.0f : 0.0f;
    float noobj = (tv[4] == 0.0f) ? 1.0f : 0.0f;

    // predicted box 1
    float b1x1 = ltx + pv[0] / 7.0f - pv[2] * 0.5f;
    float b1y1 = lty + pv[1] / 7.0f - pv[3] * 0.5f;
    float b1x2 = pv[2] + b1x1;
    float b1y2 = pv[3] + b1y1;

    // predicted box 2 (faithful: p[5:7]*(1/S - 0.5))
    const float C2 = (float)(1.0 / 7.0 - 0.5);
    float b2x1 = ltx + pv[5] * C2;
    float b2y1 = lty + pv[6] * C2;
    float b2x2 = pv[7] + b2x1;
    float b2y2 = pv[8] + b2y1;

    // target box
    float tbx1 = ltx + tv[0] / 7.0f - tv[2] * 0.5f;
    float tby1 = lty + tv[1] / 7.0f - tv[3] * 0.5f;
    float tbx2 = tv[2] + tbx1;
    float tby2 = tv[3] + tby1;

    float iou1 = iou_f(b1x1, b1y1, b1x2, b1y2, tbx1, tby1, tbx2, tby2);
    float iou2 = iou_f(b2x1, b2y1, b2x2, b2y2, tbx1, tby1, tbx2, tby2);

    bool sel = (iou1 >= iou2);
    float bx = sel ? pv[0] : pv[5];
    float by = sel ? pv[1] : pv[6];
    float bw = sel ? pv[2] : pv[7];
    float bh = sel ? pv[3] : pv[8];
    float bc = sel ? pv[4] : pv[9];

    float dx = bx - tv[0];
    float dy = by - tv[1];
    float xy_se = dx * dx + dy * dy;

    float sw = (bw > 0.0f) ? 1.0f : ((bw < 0.0f) ? -1.0f : 0.0f);
    float sh = (bh > 0.0f) ? 1.0f : ((bh < 0.0f) ? -1.0f : 0.0f);
    float dw = sw * sqrtf(fabsf(bw)) - sqrtf(tv[2]);
    float dh = sh * sqrtf(fabsf(bh)) - sqrtf(tv[3]);
    float wh_se = dw * dw + dh * dh;

    float mio = fmaxf(iou1, iou2);
    float dob = mio - bc;
    float obj_se = dob * dob;

    float d4 = pv[4] - tv[4];
    float d9 = pv[9] - tv[9];
    float noobj_se = d4 * d4 + d9 * d9;

    float lab = 0.0f;
    #pragma unroll
    for (int k = 10; k < NCH; ++k) {
        float d = pv[k] - tv[k];
        lab += d * d;
    }

    return coord * (5.0f * (xy_se + wh_se) + obj_se + lab)
         + 0.5f * noobj * noobj_se;
}

__global__ __launch_bounds__(256, 2) void yolo_loss_kernel(
    const char* __restrict__ p, const char* __restrict__ t,
    float* __restrict__ out, int ntiles, float inv_n)
{
    __shared__ char lds[2 * TILE_BYTES];   // 61440 B
    __shared__ float wave_sums[4];

    const int tid  = threadIdx.x;
    const int lane = tid & 63;
    const int wid  = tid >> 6;
    // transfer-residue: compute waves (0,1) get residues 2,3 -> 7 transfers;
    // idle waves (2,3) get residues 0,1 -> 8 transfers.
    const int xr = (wid + 2) & 3;

    float acc = 0.0f;
    int tile = blockIdx.x;
    int buf = 0;
    if (tile < ntiles) stage_tile(p, t, tile, lds, xr, lane);

    for (; tile < ntiles; tile += NBLOCKS) {
        int next = tile + NBLOCKS;
        // Drain this tile's staging loads (issued one full iteration ago),
        // then barrier: buf is ready AND everyone finished reading buf^1.
        asm volatile("s_waitcnt vmcnt(0)" ::: "memory");
        __syncthreads();
        if (next < ntiles)
            stage_tile(p, t, next, lds + (buf ^ 1) * TILE_BYTES, xr, lane);

        if (tid < TILE_CELLS) {
            const float* pvp = (const float*)(lds + buf * TILE_BYTES) + tid * NCH;
            const float* tvp = (const float*)(lds + buf * TILE_BYTES + ARR_TILE_BYTES) + tid * NCH;

            float pv[NCH], tv[NCH];
            #pragma unroll
            for (int k = 0; k < NCH / 2; ++k) {
                float2 a = ((const float2*)pvp)[k];
                float2 b = ((const float2*)tvp)[k];
                pv[2 * k] = a.x; pv[2 * k + 1] = a.y;
                tv[2 * k] = b.x; tv[2 * k + 1] = b.y;
            }

            acc += cell_loss_f(pv, tv, tile * TILE_CELLS + tid);
        }

        buf ^= 1;
    }

    acc *= inv_n;

    // wave-64 shuffle reduction
    #pragma unroll
    for (int off = 32; off > 0; off >>= 1)
        acc += __shfl_down(acc, off, 64);

    if (lane == 0) wave_sums[wid] = acc;
    __syncthreads();
    if (tid == 0) {
        atomicAdd(out, wave_sums[0] + wave_sums[1] + wave_sums[2] + wave_sums[3]);
    }
}

extern "C" void kernel_launch(void* const* d_in, const int* in_sizes, int n_in,
                              void* d_out, int out_size, void* d_ws, size_t ws_size,
                              hipStream_t stream) {
    const char* p = (const char*)d_in[0];   // modely [N,7,7,30] f32
    const char* t = (const char*)d_in[1];   // targety [N,7,7,30] f32
    float* out = (float*)d_out;

    int ncells = in_sizes[0] / NCH;                  // 401408
    int nsamples = ncells / CELLS_PER_SAMPLE;        // 8192
    int ntiles = ncells / TILE_CELLS;                // 3136 (exact)

    // d_out is poisoned before every timed launch — zero it first.
    hipMemsetAsync(out, 0, sizeof(float) * (size_t)out_size, stream);

    yolo_loss_kernel<<<NBLOCKS, 256, 0, stream>>>(
        p, t, out, ntiles, 1.0f / (float)nsamples);
}